// Round 1
// baseline (11868.491 us; speedup 1.0000x reference)
//
#include <hip/hip_runtime.h>

#define H 51
#define G4 204        // 4*H
#define TIN 512
#define TTOT 544      // TIN + future(32)
#define BTILE 8
#define WROWS 217     // max row index used = 3*51+63 = 216
#define W1STRIDE 52   // W_hh1 LDS row stride (floats), 13 float4
#define W2STRIDE 104  // ws layout: [ih2 row (52)] [hh2 row (52)]

__device__ __forceinline__ float sigf(float x) {
    return 1.0f / (1.0f + __expf(-x));
}
__device__ __forceinline__ float tanh_fast(float x) {
    // 1 - 2/(1+e^{2x}); saturates correctly at +-1 for large |x|
    return 1.0f - 2.0f / (1.0f + __expf(2.0f * x));
}

// Pack W_ih2 / W_hh2 into workspace with 16B-aligned padded rows, zero-filled
// pads (so pad-column k=51 contributes 0 against garbage h[51]).
__global__ void prep_w2(const float* __restrict__ Wih2,
                        const float* __restrict__ Whh2,
                        float* __restrict__ W2) {
    int i = blockIdx.x * blockDim.x + threadIdx.x;
    const int total = WROWS * W2STRIDE;
    for (; i < total; i += gridDim.x * blockDim.x) {
        int r = i / W2STRIDE;
        int c = i - r * W2STRIDE;
        float v = 0.0f;
        if (r < G4) {
            if (c < H) v = Wih2[r * H + c];
            else if (c >= 52 && c < 52 + H) v = Whh2[r * H + (c - 52)];
        }
        W2[i] = v;
    }
}

__global__ __launch_bounds__(512, 2) void lstm_seq(
    const float* __restrict__ input,   // [2048][512]
    const float* __restrict__ W_ih1,   // [204] (column matrix [204,1])
    const float* __restrict__ W_hh1,   // [204][51]
    const float* __restrict__ b_ih1,   // [204]
    const float* __restrict__ b_hh1,   // [204]
    const float* __restrict__ b_ih2,   // [204]
    const float* __restrict__ b_hh2,   // [204]
    const float* __restrict__ W_lin,   // [51]
    const float* __restrict__ b_lin,   // [1]
    const float* __restrict__ W2,      // ws-packed [217][104]
    float* __restrict__ out)           // [2048][544]
{
    __shared__ __align__(16) float sW1[WROWS * W1STRIDE];   // 45.1 KB
    __shared__ __align__(16) float sH1[2][BTILE][68];       // 4.35 KB
    __shared__ __align__(16) float sH2[2][BTILE][68];       // 4.35 KB
    __shared__ float sWlin[64];
    __shared__ float sXfb[BTILE];

    const int tid  = threadIdx.x;
    const int lane = tid & 63;
    const int wv   = tid >> 6;           // wave 0..7
    const int u    = wv * 8 + (lane >> 3); // unit 0..63 (51 real + pad)
    const int b    = lane & 7;           // batch-in-tile 0..7
    const int b0   = blockIdx.x * BTILE;

    // Stage W_hh1 into LDS with zero pads (rows>=204, cols>=51 are zero).
    for (int i = tid; i < WROWS * W1STRIDE; i += 512) {
        int r = i / W1STRIDE;
        int k = i - r * W1STRIDE;
        sW1[i] = (r < G4 && k < H) ? W_hh1[r * H + k] : 0.0f;
    }
    if (tid < 64) sWlin[tid] = (tid < H) ? W_lin[tid] : 0.0f;
    {   // zero both h double-buffers
        float* p1 = &sH1[0][0][0];
        float* p2 = &sH2[0][0][0];
        for (int i = tid; i < 2 * BTILE * 68; i += 512) { p1[i] = 0.0f; p2[i] = 0.0f; }
    }

    // Per-thread constants: combined biases + input weights for the 4 gates of unit u.
    float zb1[4], wx1[4], zb2[4];
    #pragma unroll
    for (int g = 0; g < 4; ++g) {
        int r = g * H + u;
        int rc = r > (G4 - 1) ? (G4 - 1) : r;   // clamp: pad lanes read real-but-unused data
        zb1[g] = b_ih1[rc] + b_hh1[rc];
        wx1[g] = W_ih1[rc];
        zb2[g] = b_ih2[rc] + b_hh2[rc];
    }
    const float blin = b_lin[0];

    const float4* w1p[4];
    const float4* w2pa[4];
    const float4* w2pb[4];
    #pragma unroll
    for (int g = 0; g < 4; ++g) {
        int r = g * H + u;                       // <= 216, padded storage is defined
        w1p[g]  = (const float4*)&sW1[r * W1STRIDE];
        w2pa[g] = (const float4*)&W2[r * W2STRIDE];
        w2pb[g] = (const float4*)&W2[r * W2STRIDE + 52];
    }

    float c1 = 0.0f, c2 = 0.0f;   // cell state for (u, b) lives in registers

    __syncthreads();

    for (int t = 0; t < TTOT; ++t) {
        const int cur = t & 1;
        const int nxt = cur ^ 1;

        float x;
        if (t < TIN) x = input[(size_t)(b0 + b) * TIN + t];
        else         x = sXfb[b];

        // ---- layer 1: z = W_ih1*x + (b_ih1+b_hh1) + W_hh1 @ h1 ----
        float a0 = zb1[0] + wx1[0] * x;
        float a1 = zb1[1] + wx1[1] * x;
        float a2 = zb1[2] + wx1[2] * x;
        float a3 = zb1[3] + wx1[3] * x;
        {
            const float4* hv = (const float4*)&sH1[cur][b][0];
            #pragma unroll
            for (int kk = 0; kk < 13; ++kk) {
                float4 h4 = hv[kk];
                float4 q0 = w1p[0][kk];
                float4 q1 = w1p[1][kk];
                float4 q2 = w1p[2][kk];
                float4 q3 = w1p[3][kk];
                a0 += q0.x*h4.x + q0.y*h4.y + q0.z*h4.z + q0.w*h4.w;
                a1 += q1.x*h4.x + q1.y*h4.y + q1.z*h4.z + q1.w*h4.w;
                a2 += q2.x*h4.x + q2.y*h4.y + q2.z*h4.z + q2.w*h4.w;
                a3 += q3.x*h4.x + q3.y*h4.y + q3.z*h4.z + q3.w*h4.w;
            }
        }
        {
            float ig = sigf(a0);
            float fg = sigf(a1);
            float gg = tanh_fast(a2);
            float og = sigf(a3);
            c1 = fg * c1 + ig * gg;
            sH1[nxt][b][u] = og * tanh_fast(c1);
        }
        __syncthreads();

        // ---- layer 2: z = (b_ih2+b_hh2) + W_ih2 @ h1_new + W_hh2 @ h2 ----
        a0 = zb2[0]; a1 = zb2[1]; a2 = zb2[2]; a3 = zb2[3];
        {
            const float4* hv = (const float4*)&sH1[nxt][b][0];
            #pragma unroll
            for (int kk = 0; kk < 13; ++kk) {
                float4 h4 = hv[kk];
                float4 q0 = w2pa[0][kk];
                float4 q1 = w2pa[1][kk];
                float4 q2 = w2pa[2][kk];
                float4 q3 = w2pa[3][kk];
                a0 += q0.x*h4.x + q0.y*h4.y + q0.z*h4.z + q0.w*h4.w;
                a1 += q1.x*h4.x + q1.y*h4.y + q1.z*h4.z + q1.w*h4.w;
                a2 += q2.x*h4.x + q2.y*h4.y + q2.z*h4.z + q2.w*h4.w;
                a3 += q3.x*h4.x + q3.y*h4.y + q3.z*h4.z + q3.w*h4.w;
            }
        }
        {
            const float4* hv = (const float4*)&sH2[cur][b][0];
            #pragma unroll
            for (int kk = 0; kk < 13; ++kk) {
                float4 h4 = hv[kk];
                float4 q0 = w2pb[0][kk];
                float4 q1 = w2pb[1][kk];
                float4 q2 = w2pb[2][kk];
                float4 q3 = w2pb[3][kk];
                a0 += q0.x*h4.x + q0.y*h4.y + q0.z*h4.z + q0.w*h4.w;
                a1 += q1.x*h4.x + q1.y*h4.y + q1.z*h4.z + q1.w*h4.w;
                a2 += q2.x*h4.x + q2.y*h4.y + q2.z*h4.z + q2.w*h4.w;
                a3 += q3.x*h4.x + q3.y*h4.y + q3.z*h4.z + q3.w*h4.w;
            }
        }
        {
            float ig = sigf(a0);
            float fg = sigf(a1);
            float gg = tanh_fast(a2);
            float og = sigf(a3);
            c2 = fg * c2 + ig * gg;
            sH2[nxt][b][u] = og * tanh_fast(c2);
        }
        __syncthreads();

        // ---- output head: out[b] = W_lin @ h2_new + b_lin (wave 0 only) ----
        if (tid < 64) {
            int bb = tid >> 3, kc = tid & 7;
            float p = 0.0f;
            for (int k = kc; k < H; k += 8) p += sWlin[k] * sH2[nxt][bb][k];
            p += __shfl_xor(p, 4);
            p += __shfl_xor(p, 2);
            p += __shfl_xor(p, 1);
            if (kc == 0) {
                float val = p + blin;
                out[(size_t)(b0 + bb) * TTOT + t] = val;
                sXfb[bb] = val;   // autoregressive feedback for t >= TIN
            }
        }
        __syncthreads();   // protects sXfb and buffer reuse before next step
    }
}

extern "C" void kernel_launch(void* const* d_in, const int* in_sizes, int n_in,
                              void* d_out, int out_size, void* d_ws, size_t ws_size,
                              hipStream_t stream) {
    const float* input = (const float*)d_in[0];
    const float* W_ih1 = (const float*)d_in[1];
    const float* W_hh1 = (const float*)d_in[2];
    const float* b_ih1 = (const float*)d_in[3];
    const float* b_hh1 = (const float*)d_in[4];
    const float* W_ih2 = (const float*)d_in[5];
    const float* W_hh2 = (const float*)d_in[6];
    const float* b_ih2 = (const float*)d_in[7];
    const float* b_hh2 = (const float*)d_in[8];
    const float* W_lin = (const float*)d_in[9];
    const float* b_lin = (const float*)d_in[10];
    // d_in[11] = future (device scalar) — fixed at 32, compiled in.
    float* out = (float*)d_out;
    float* W2  = (float*)d_ws;   // needs 217*104*4 = 90,272 B of workspace

    prep_w2<<<dim3(90), dim3(256), 0, stream>>>(W_ih2, W_hh2, W2);
    lstm_seq<<<dim3(256), dim3(512), 0, stream>>>(input, W_ih1, W_hh1, b_ih1, b_hh1,
                                                  b_ih2, b_hh2, W_lin, b_lin, W2, out);
}

// Round 2
// 2252.486 us; speedup vs baseline: 5.2691x; 5.2691x over previous
//
#include <hip/hip_runtime.h>

#define H 51
#define TIN 512
#define TTOT 544      // TIN + future(32)
#define BTILE 8

__device__ __forceinline__ float fast_rcp(float x) { return __builtin_amdgcn_rcpf(x); }
__device__ __forceinline__ float sigf(float x)  { return fast_rcp(1.0f + __expf(-x)); }
__device__ __forceinline__ float tanhf_(float x){ return 1.0f - 2.0f * fast_rcp(1.0f + __expf(2.0f * x)); }

// Thread map (512 thr/block, 1 block/CU, 256 blocks):
//   lane bits: [0:1]=q (k-phase mod 4), [2]=bh (batch half), [3:5]+wave = u (unit 0..63)
//   Weights live in REGISTERS (156 floats/thread, loaded once) -> zero per-step
//   weight traffic. h-state in LDS [2][64][8]. Cell state c for (u, my_b) in regs.
//   Per step: partial gate sums over k=q+4j for 4 b's, then 2-stage shfl_xor
//   butterfly over q reduce-scatters to 1 b per thread.
__global__ __launch_bounds__(512, 2) void lstm_seq(
    const float* __restrict__ input,   // [2048][512]
    const float* __restrict__ W_ih1,   // [204]
    const float* __restrict__ W_hh1,   // [204][51]
    const float* __restrict__ b_ih1,   // [204]
    const float* __restrict__ b_hh1,   // [204]
    const float* __restrict__ W_ih2,   // [204][51]
    const float* __restrict__ W_hh2,   // [204][51]
    const float* __restrict__ b_ih2,   // [204]
    const float* __restrict__ b_hh2,   // [204]
    const float* __restrict__ W_lin,   // [51]
    const float* __restrict__ b_lin,   // [1]
    float* __restrict__ out)           // [2048][544]
{
    __shared__ __align__(16) float sH1[2][64][8];   // 4 KB, [buf][k/unit][b]
    __shared__ __align__(16) float sH2[2][64][8];   // 4 KB
    __shared__ float sWlin[64];
    __shared__ float sXfb[8];

    const int tid  = threadIdx.x;
    const int lane = tid & 63;
    const int wv   = tid >> 6;
    const int u    = wv * 8 + (lane >> 3);
    const int q    = lane & 3;
    const int bh   = (lane >> 2) & 1;
    const int my_b = bh * 4 + 2 * (q & 1) + (q >> 1);  // owner batch after butterfly
    const int b0   = blockIdx.x * BTILE;

    const int ur = (u < H) ? u : (H - 1);   // clamp pad units (their outputs never read)

    // ---- load persistent register weights: k = q + 4*j ----
    float w1[4][13], w2a[4][13], w2b[4][13];
    float zb1[4], wx1[4], zb2[4];
    #pragma unroll
    for (int g = 0; g < 4; ++g) {
        const int r = g * H + ur;
        zb1[g] = b_ih1[r] + b_hh1[r];
        wx1[g] = W_ih1[r];
        zb2[g] = b_ih2[r] + b_hh2[r];
        #pragma unroll
        for (int j = 0; j < 13; ++j) {
            const int k = q + 4 * j;
            const bool ok = (k < H);
            w1 [g][j] = ok ? W_hh1[r * H + k] : 0.0f;
            w2a[g][j] = ok ? W_ih2[r * H + k] : 0.0f;
            w2b[g][j] = ok ? W_hh2[r * H + k] : 0.0f;
        }
    }
    const float blin = b_lin[0];

    if (tid < 64) sWlin[tid] = (tid < H) ? W_lin[tid] : 0.0f;
    {
        float* p1 = &sH1[0][0][0];
        float* p2 = &sH2[0][0][0];
        for (int i = tid; i < 2 * 64 * 8; i += 512) { p1[i] = 0.0f; p2[i] = 0.0f; }
    }
    float c1 = 0.0f, c2 = 0.0f;
    __syncthreads();

    for (int t = 0; t < TTOT; ++t) {
        const int cur = t & 1, nxt = cur ^ 1;

        float x;
        if (t < TIN) x = input[(size_t)(b0 + my_b) * TIN + t];
        else         x = sXfb[my_b];

        float a[4][4];   // [gate][b-in-half]

        // ---- layer 1 partials: W_hh1 @ h1 ----
        #pragma unroll
        for (int g = 0; g < 4; ++g)
            #pragma unroll
            for (int i = 0; i < 4; ++i) a[g][i] = 0.0f;
        #pragma unroll
        for (int j = 0; j < 13; ++j) {
            const int k = q + 4 * j;                       // <= 51, row 51 is pad
            float4 h4 = ((const float4*)&sH1[cur][k][0])[bh];
            #pragma unroll
            for (int g = 0; g < 4; ++g) {
                a[g][0] += w1[g][j] * h4.x;
                a[g][1] += w1[g][j] * h4.y;
                a[g][2] += w1[g][j] * h4.z;
                a[g][3] += w1[g][j] * h4.w;
            }
        }
        // butterfly reduce-scatter over q (lane bits 0,1)
        float zg[4];
        #pragma unroll
        for (int g = 0; g < 4; ++g) {
            float t0 = __shfl_xor(a[g][0], 1);
            float t1 = __shfl_xor(a[g][1], 1);
            float t2 = __shfl_xor(a[g][2], 1);
            float t3 = __shfl_xor(a[g][3], 1);
            float s0 = (q & 1) ? (a[g][2] + t2) : (a[g][0] + t0);
            float s1 = (q & 1) ? (a[g][3] + t3) : (a[g][1] + t1);
            float r0 = __shfl_xor(s0, 2);
            float r1 = __shfl_xor(s1, 2);
            zg[g] = (q & 2) ? (s1 + r1) : (s0 + r0);
        }
        {
            float zi = zg[0] + zb1[0] + wx1[0] * x;
            float zf = zg[1] + zb1[1] + wx1[1] * x;
            float zc = zg[2] + zb1[2] + wx1[2] * x;
            float zo = zg[3] + zb1[3] + wx1[3] * x;
            float ig = sigf(zi), fg = sigf(zf), gg = tanhf_(zc), og = sigf(zo);
            c1 = fg * c1 + ig * gg;
            sH1[nxt][u][my_b] = og * tanhf_(c1);
        }
        __syncthreads();

        // ---- layer 2 partials: W_ih2 @ h1_new + W_hh2 @ h2 ----
        #pragma unroll
        for (int g = 0; g < 4; ++g)
            #pragma unroll
            for (int i = 0; i < 4; ++i) a[g][i] = 0.0f;
        #pragma unroll
        for (int j = 0; j < 13; ++j) {
            const int k = q + 4 * j;
            float4 ha = ((const float4*)&sH1[nxt][k][0])[bh];
            float4 hb = ((const float4*)&sH2[cur][k][0])[bh];
            #pragma unroll
            for (int g = 0; g < 4; ++g) {
                a[g][0] += w2a[g][j] * ha.x + w2b[g][j] * hb.x;
                a[g][1] += w2a[g][j] * ha.y + w2b[g][j] * hb.y;
                a[g][2] += w2a[g][j] * ha.z + w2b[g][j] * hb.z;
                a[g][3] += w2a[g][j] * ha.w + w2b[g][j] * hb.w;
            }
        }
        #pragma unroll
        for (int g = 0; g < 4; ++g) {
            float t0 = __shfl_xor(a[g][0], 1);
            float t1 = __shfl_xor(a[g][1], 1);
            float t2 = __shfl_xor(a[g][2], 1);
            float t3 = __shfl_xor(a[g][3], 1);
            float s0 = (q & 1) ? (a[g][2] + t2) : (a[g][0] + t0);
            float s1 = (q & 1) ? (a[g][3] + t3) : (a[g][1] + t1);
            float r0 = __shfl_xor(s0, 2);
            float r1 = __shfl_xor(s1, 2);
            zg[g] = (q & 2) ? (s1 + r1) : (s0 + r0);
        }
        {
            float zi = zg[0] + zb2[0];
            float zf = zg[1] + zb2[1];
            float zc = zg[2] + zb2[2];
            float zo = zg[3] + zb2[3];
            float ig = sigf(zi), fg = sigf(zf), gg = tanhf_(zc), og = sigf(zo);
            c2 = fg * c2 + ig * gg;
            sH2[nxt][u][my_b] = og * tanhf_(c2);
        }
        __syncthreads();

        // ---- output head: out = W_lin @ h2_new + b_lin (wave 0) ----
        if (tid < 64) {
            const int b = tid >> 3, kc = tid & 7;
            float p = 0.0f;
            #pragma unroll
            for (int jj = 0; jj < 8; ++jj) {
                const int k = kc + 8 * jj;                 // rows >= 51: sWlin = 0
                p += sWlin[k] * sH2[nxt][k][b];
            }
            p += __shfl_xor(p, 1);
            p += __shfl_xor(p, 2);
            p += __shfl_xor(p, 4);
            if (kc == 0) {
                float val = p + blin;
                out[(size_t)(b0 + b) * TTOT + t] = val;
                sXfb[b] = val;
            }
        }
        __syncthreads();   // protects sXfb + h double-buffer rotation
    }
}

extern "C" void kernel_launch(void* const* d_in, const int* in_sizes, int n_in,
                              void* d_out, int out_size, void* d_ws, size_t ws_size,
                              hipStream_t stream) {
    const float* input = (const float*)d_in[0];
    const float* W_ih1 = (const float*)d_in[1];
    const float* W_hh1 = (const float*)d_in[2];
    const float* b_ih1 = (const float*)d_in[3];
    const float* b_hh1 = (const float*)d_in[4];
    const float* W_ih2 = (const float*)d_in[5];
    const float* W_hh2 = (const float*)d_in[6];
    const float* b_ih2 = (const float*)d_in[7];
    const float* b_hh2 = (const float*)d_in[8];
    const float* W_lin = (const float*)d_in[9];
    const float* b_lin = (const float*)d_in[10];
    // d_in[11] = future (=32), compiled in.
    float* out = (float*)d_out;

    lstm_seq<<<dim3(256), dim3(512), 0, stream>>>(input, W_ih1, W_hh1, b_ih1, b_hh1,
                                                  W_ih2, W_hh2, b_ih2, b_hh2,
                                                  W_lin, b_lin, out);
}

// Round 3
// 2173.726 us; speedup vs baseline: 5.4600x; 1.0362x over previous
//
#include <hip/hip_runtime.h>

#define H 51
#define TIN 512
#define TTOT 544      // TIN + future(32)
#define BTILE 8

__device__ __forceinline__ float fast_rcp(float x) { return __builtin_amdgcn_rcpf(x); }
__device__ __forceinline__ float sigf(float x)  { return fast_rcp(1.0f + __expf(-x)); }
__device__ __forceinline__ float tanhf_(float x){ return 1.0f - 2.0f * fast_rcp(1.0f + __expf(2.0f * x)); }

// Thread map (512 thr/block, 1 block/CU, 256 blocks):
//   lane bits: [0:1]=q (k-phase mod 4), [2]=bh (batch half), [3:5]+wave = u (unit 0..63)
//   Weights in REGISTERS (156 floats/thread). amdgpu_waves_per_eu(2,2) pins the
//   allocator at 2 waves/EU -> 256 VGPR budget -> no AGPR spill (R2 failure mode:
//   compiler chose 128 VGPRs and ping-ponged weights through v_accvgpr_*).
__global__ __launch_bounds__(512)
__attribute__((amdgpu_waves_per_eu(2, 2)))
void lstm_seq(
    const float* __restrict__ input,   // [2048][512]
    const float* __restrict__ W_ih1,   // [204]
    const float* __restrict__ W_hh1,   // [204][51]
    const float* __restrict__ b_ih1,   // [204]
    const float* __restrict__ b_hh1,   // [204]
    const float* __restrict__ W_ih2,   // [204][51]
    const float* __restrict__ W_hh2,   // [204][51]
    const float* __restrict__ b_ih2,   // [204]
    const float* __restrict__ b_hh2,   // [204]
    const float* __restrict__ W_lin,   // [51]
    const float* __restrict__ b_lin,   // [1]
    float* __restrict__ out)           // [2048][544]
{
    __shared__ __align__(16) float sH1[2][64][8];   // [buf][k/unit][b]
    __shared__ __align__(16) float sH2[2][64][8];
    __shared__ float sWlin[64];
    __shared__ float sXfb[8];

    const int tid  = threadIdx.x;
    const int lane = tid & 63;
    const int wv   = tid >> 6;
    const int u    = wv * 8 + (lane >> 3);
    const int q    = lane & 3;
    const int bh   = (lane >> 2) & 1;
    const int my_b = bh * 4 + 2 * (q & 1) + (q >> 1);  // owner batch after butterfly
    const int b0   = blockIdx.x * BTILE;

    const int ur = (u < H) ? u : (H - 1);   // clamp pad units (their outputs never read)

    // ---- persistent register weights: k = q + 4*j ----
    float w1[4][13], w2a[4][13], w2b[4][13];
    float zb1[4], wx1[4], zb2[4];
    #pragma unroll
    for (int g = 0; g < 4; ++g) {
        const int r = g * H + ur;
        zb1[g] = b_ih1[r] + b_hh1[r];
        wx1[g] = W_ih1[r];
        zb2[g] = b_ih2[r] + b_hh2[r];
        #pragma unroll
        for (int j = 0; j < 13; ++j) {
            const int k = q + 4 * j;
            const bool ok = (k < H);        // zero k=51 pad col: kills garbage h[51]
            w1 [g][j] = ok ? W_hh1[r * H + k] : 0.0f;
            w2a[g][j] = ok ? W_ih2[r * H + k] : 0.0f;
            w2b[g][j] = ok ? W_hh2[r * H + k] : 0.0f;
        }
    }
    const float blin = b_lin[0];

    if (tid < 64) sWlin[tid] = (tid < H) ? W_lin[tid] : 0.0f;
    {
        float* p1 = &sH1[0][0][0];
        float* p2 = &sH2[0][0][0];
        for (int i = tid; i < 2 * 64 * 8; i += 512) { p1[i] = 0.0f; p2[i] = 0.0f; }
    }
    float c1 = 0.0f, c2 = 0.0f;
    __syncthreads();

    for (int t = 0; t < TTOT; ++t) {
        const int cur = t & 1, nxt = cur ^ 1;

        float x;
        if (t < TIN) x = input[(size_t)(b0 + my_b) * TIN + t];
        else         x = sXfb[my_b];

        float a[4][4];   // [gate][b-in-half]

        // ---- layer 1 partials: W_hh1 @ h1 ----
        #pragma unroll
        for (int g = 0; g < 4; ++g)
            #pragma unroll
            for (int i = 0; i < 4; ++i) a[g][i] = 0.0f;
        #pragma unroll
        for (int j = 0; j < 13; ++j) {
            const int k = q + 4 * j;
            float4 h4 = ((const float4*)&sH1[cur][k][0])[bh];
            #pragma unroll
            for (int g = 0; g < 4; ++g) {
                a[g][0] += w1[g][j] * h4.x;
                a[g][1] += w1[g][j] * h4.y;
                a[g][2] += w1[g][j] * h4.z;
                a[g][3] += w1[g][j] * h4.w;
            }
        }
        // butterfly reduce-scatter over q (lane bits 0,1)
        float zg[4];
        #pragma unroll
        for (int g = 0; g < 4; ++g) {
            float t0 = __shfl_xor(a[g][0], 1);
            float t1 = __shfl_xor(a[g][1], 1);
            float t2 = __shfl_xor(a[g][2], 1);
            float t3 = __shfl_xor(a[g][3], 1);
            float s0 = (q & 1) ? (a[g][2] + t2) : (a[g][0] + t0);
            float s1 = (q & 1) ? (a[g][3] + t3) : (a[g][1] + t1);
            float r0 = __shfl_xor(s0, 2);
            float r1 = __shfl_xor(s1, 2);
            zg[g] = (q & 2) ? (s1 + r1) : (s0 + r0);
        }
        {
            float zi = zg[0] + zb1[0] + wx1[0] * x;
            float zf = zg[1] + zb1[1] + wx1[1] * x;
            float zc = zg[2] + zb1[2] + wx1[2] * x;
            float zo = zg[3] + zb1[3] + wx1[3] * x;
            float ig = sigf(zi), fg = sigf(zf), gg = tanhf_(zc), og = sigf(zo);
            c1 = fg * c1 + ig * gg;
            sH1[nxt][u][my_b] = og * tanhf_(c1);
        }
        __syncthreads();

        // ---- layer 2 partials: W_ih2 @ h1_new + W_hh2 @ h2 ----
        #pragma unroll
        for (int g = 0; g < 4; ++g)
            #pragma unroll
            for (int i = 0; i < 4; ++i) a[g][i] = 0.0f;
        #pragma unroll
        for (int j = 0; j < 13; ++j) {
            const int k = q + 4 * j;
            float4 ha = ((const float4*)&sH1[nxt][k][0])[bh];
            float4 hb = ((const float4*)&sH2[cur][k][0])[bh];
            #pragma unroll
            for (int g = 0; g < 4; ++g) {
                a[g][0] += w2a[g][j] * ha.x + w2b[g][j] * hb.x;
                a[g][1] += w2a[g][j] * ha.y + w2b[g][j] * hb.y;
                a[g][2] += w2a[g][j] * ha.z + w2b[g][j] * hb.z;
                a[g][3] += w2a[g][j] * ha.w + w2b[g][j] * hb.w;
            }
        }
        #pragma unroll
        for (int g = 0; g < 4; ++g) {
            float t0 = __shfl_xor(a[g][0], 1);
            float t1 = __shfl_xor(a[g][1], 1);
            float t2 = __shfl_xor(a[g][2], 1);
            float t3 = __shfl_xor(a[g][3], 1);
            float s0 = (q & 1) ? (a[g][2] + t2) : (a[g][0] + t0);
            float s1 = (q & 1) ? (a[g][3] + t3) : (a[g][1] + t1);
            float r0 = __shfl_xor(s0, 2);
            float r1 = __shfl_xor(s1, 2);
            zg[g] = (q & 2) ? (s1 + r1) : (s0 + r0);
        }
        {
            float zi = zg[0] + zb2[0];
            float zf = zg[1] + zb2[1];
            float zc = zg[2] + zb2[2];
            float zo = zg[3] + zb2[3];
            float ig = sigf(zi), fg = sigf(zf), gg = tanhf_(zc), og = sigf(zo);
            c2 = fg * c2 + ig * gg;
            sH2[nxt][u][my_b] = og * tanhf_(c2);
        }
        __syncthreads();

        // ---- output head: out = W_lin @ h2_new + b_lin (wave 0) ----
        if (tid < 64) {
            const int b = tid >> 3, kc = tid & 7;
            float p = 0.0f;
            #pragma unroll
            for (int jj = 0; jj < 8; ++jj) {
                const int k = kc + 8 * jj;                 // rows >= 51: sWlin = 0
                p += sWlin[k] * sH2[nxt][k][b];
            }
            p += __shfl_xor(p, 1);
            p += __shfl_xor(p, 2);
            p += __shfl_xor(p, 4);
            if (kc == 0) {
                float val = p + blin;
                out[(size_t)(b0 + b) * TTOT + t] = val;
                sXfb[b] = val;
            }
        }
        // sXfb (feedback) is only consumed at t+1 >= TIN; the head's sH2[nxt]
        // reads are safe without this barrier (next step writes the OTHER
        // buffer, and wave0 can't fall 2 steps behind across B1/B2).
        if (t >= TIN - 1) __syncthreads();
    }
}

extern "C" void kernel_launch(void* const* d_in, const int* in_sizes, int n_in,
                              void* d_out, int out_size, void* d_ws, size_t ws_size,
                              hipStream_t stream) {
    const float* input = (const float*)d_in[0];
    const float* W_ih1 = (const float*)d_in[1];
    const float* W_hh1 = (const float*)d_in[2];
    const float* b_ih1 = (const float*)d_in[3];
    const float* b_hh1 = (const float*)d_in[4];
    const float* W_ih2 = (const float*)d_in[5];
    const float* W_hh2 = (const float*)d_in[6];
    const float* b_ih2 = (const float*)d_in[7];
    const float* b_hh2 = (const float*)d_in[8];
    const float* W_lin = (const float*)d_in[9];
    const float* b_lin = (const float*)d_in[10];
    // d_in[11] = future (=32), compiled in.
    float* out = (float*)d_out;

    lstm_seq<<<dim3(256), dim3(512), 0, stream>>>(input, W_ih1, W_hh1, b_ih1, b_hh1,
                                                  W_ih2, W_hh2, b_ih2, b_hh2,
                                                  W_lin, b_lin, out);
}